// Round 4
// baseline (299.404 us; speedup 1.0000x reference)
//
#include <hip/hip_runtime.h>

#define DIM 256
#define KCODES 1024
#define LEVELS 4
#define CHUNK 64
#define NCHUNK 16
#define TOKB 128                 // tokens per block: 2 waves x 64 tokens
#define NTOK 65536
#define NELEM (NTOK * DIM)

typedef _Float16 h8 __attribute__((ext_vector_type(8)));
typedef _Float16 h4 __attribute__((ext_vector_type(4)));
typedef _Float16 h2 __attribute__((ext_vector_type(2)));
typedef float f4 __attribute__((ext_vector_type(4)));
typedef float f16v __attribute__((ext_vector_type(16)));
typedef unsigned int u32;

__device__ __forceinline__ void gload16(const void* g, void* l) {
  __builtin_amdgcn_global_load_lds(
      (const __attribute__((address_space(1))) void*)g,
      (__attribute__((address_space(3))) void*)l, 16, 0, 0);
}

__device__ __forceinline__ float sq8(h8 r, float acc) {
#if __has_builtin(__builtin_amdgcn_fdot2)
  #pragma unroll
  for (int j = 0; j < 4; ++j) {
    h2 p = {r[2 * j], r[2 * j + 1]};
    acc = __builtin_amdgcn_fdot2(p, p, acc, false);
  }
#else
  #pragma unroll
  for (int j = 0; j < 8; ++j) { float v = (float)r[j]; acc += v * v; }
#endif
  return acc;
}

// Phase 0: cb fp32 -> fp16; e2p = 0.25 - 0.5*||e||^2 (positive-score shift for
// the 2-op argmax tracker). Also zeroes the commit accumulator.
__global__ __launch_bounds__(256) void rvq_prep(const float* __restrict__ cb,
                                                _Float16* __restrict__ cb16,
                                                float* __restrict__ e2p,
                                                float* __restrict__ out) {
  if (blockIdx.x == 0 && threadIdx.x == 0) out[NELEM] = 0.0f;
  const int row = blockIdx.x * 4 + (threadIdx.x >> 6);
  const int lane = threadIdx.x & 63;
  const float* src = cb + (size_t)row * DIM + lane * 4;
  f4 v = *(const f4*)src;
  h4 hv;
  hv[0] = (_Float16)v[0]; hv[1] = (_Float16)v[1];
  hv[2] = (_Float16)v[2]; hv[3] = (_Float16)v[3];
  *(h4*)(cb16 + (size_t)row * DIM + lane * 4) = hv;
  float s = v[0]*v[0] + v[1]*v[1] + v[2]*v[2] + v[3]*v[3];
  #pragma unroll
  for (int off = 32; off; off >>= 1) s += __shfl_xor(s, off, 64);
  if (lane == 0) e2p[row] = 0.25f - 0.5f * s;
}

// Main fused RVQ, 32x32x16 MFMA edition. Block = 2 waves; wave owns 64 tokens
// (2 m-tiles of 32). 32x32x16 consumes the same 16B/lane of B per MFMA as
// 16x16x32 but does 2x the FLOPs -> LDS read count halves (the r3 bottleneck).
// A-frag layout: token m=lane&31, dims k = kk*16 + (lane>>5)*8 + j -> residual
// lives as af[2][16] h8 (128 VGPRs), updated in fp16 in-lane.
// C/D layout (m74/m101-verified): code col=lane&31,
// token row=(reg&3)+8*(reg>>2)+4*(lane>>5).
__global__ __launch_bounds__(128, 1) void rvq_main(
    const float* __restrict__ x, const float* __restrict__ cb32,
    const _Float16* __restrict__ cb16, const float* __restrict__ e2p,
    float* __restrict__ out) {
  __shared__ __attribute__((aligned(16))) _Float16 clds[2][CHUNK * DIM];  // 64 KB
  __shared__ float e2_lds[KCODES];                                        // 4 KB
  __shared__ __attribute__((aligned(16))) int idx_hist[TOKB][4];          // 2 KB
  __shared__ float r2_sh[TOKB];
  __shared__ float csum_sh[2];

  const int tid = threadIdx.x;
  const int wave = tid >> 6, lane = tid & 63;
  const int col = lane & 31, Lhi = lane >> 5;

  // staging: call i covers rows (wave*32 + 2i + Lhi); lane fills row position
  // p = col, fetching global granule g = p ^ (row&7) (XOR swizzle, self-inv).
  int soff[16];
  #pragma unroll
  for (int i = 0; i < 16; ++i) {
    const int rl = wave * 32 + 2 * i + Lhi;
    soff[i] = rl * 512 + ((col ^ (rl & 7)) << 4);
  }
  // read swizzle: granule g = kk*2 + Lhi of row (nt*32+col);
  // pos = (g & ~7) | ((g ^ col) & 7); split: swz4[kk&3] + (kk>>2)*128 (imm)
  int swz4[4];
  #pragma unroll
  for (int m = 0; m < 4; ++m)
    swz4[m] = (((((m << 1) | Lhi) ^ col) & 7) << 4);

  const char* cb16b = (const char*)cb16;
  // issue chunk 0 staging immediately; flies during x-init
  {
    char* ldst = (char*)&clds[0][0] + wave * 16384;
    #pragma unroll
    for (int i = 0; i < 16; ++i) gload16(cb16b + soff[i], ldst + i * 1024);
  }

  // ---- init: x -> fp16 A-frags + r2 partials ----
  h8 af[2][16];
  float r2p[2] = {0.f, 0.f};
  const size_t tok0 = (size_t)blockIdx.x * TOKB + wave * 64;
  #pragma unroll
  for (int mt = 0; mt < 2; ++mt) {
    const float* xr = x + (tok0 + mt * 32 + col) * DIM + Lhi * 8;
    #pragma unroll
    for (int kk = 0; kk < 16; ++kk) {
      f4 a = *(const f4*)(xr + kk * 16);
      f4 b = *(const f4*)(xr + kk * 16 + 4);
      h8 h;
      #pragma unroll
      for (int j = 0; j < 4; ++j) { h[j] = (_Float16)a[j]; h[4 + j] = (_Float16)b[j]; }
      af[mt][kk] = h;
      r2p[mt] = sq8(h, r2p[mt]);
    }
  }

  float commit_acc = 0.f;

  for (int lvl = 0; lvl < LEVELS; ++lvl) {
    // residual norms -> LDS (lanes L, L+32 hold complementary dim halves)
    #pragma unroll
    for (int mt = 0; mt < 2; ++mt) {
      float s = r2p[mt] + __shfl_xor(r2p[mt], 32, 64);
      if (Lhi == 0) r2_sh[wave * 64 + mt * 32 + col] = s;
    }
    // this level's shifted-e2 table (128 threads x 8 floats)
    *(f4*)&e2_lds[tid * 8] = *(const f4*)(e2p + (lvl << 10) + tid * 8);
    *(f4*)&e2_lds[tid * 8 + 4] = *(const f4*)(e2p + (lvl << 10) + tid * 8 + 4);

    u32 best[2][16];
    #pragma unroll
    for (int mt = 0; mt < 2; ++mt)
      #pragma unroll
      for (int i = 0; i < 16; ++i) best[mt][i] = 0u;

    for (int c = 0; c < NCHUNK; ++c) {
      __syncthreads();  // staging of chunk c (issued a full phase ago) visible
      {
        const int gn = lvl * NCHUNK + c + 1;  // contiguous across levels
        const char* gsrc = cb16b + ((size_t)(gn < 64 ? gn : 63) << 15);
        char* ldst = (char*)&clds[(c + 1) & 1][0] + wave * 16384;
        #pragma unroll
        for (int i = 0; i < 16; ++i) gload16(gsrc + soff[i], ldst + i * 1024);
      }

      const char* cbuf = (const char*)&clds[c & 1][0] + col * 512;
      #pragma unroll
      for (int nt = 0; nt < 2; ++nt) {
        const int code0 = c * 64 + nt * 32;
        const float e2v = e2_lds[code0 + col];  // 0.25 - ||e||^2/2
        f16v acc0, acc1;
        #pragma unroll
        for (int i = 0; i < 16; ++i) { acc0[i] = e2v; acc1[i] = e2v; }
        #pragma unroll
        for (int kk = 0; kk < 16; ++kk) {
          h8 b = *(const h8*)(cbuf + nt * 16384 + swz4[kk & 3] + ((kk >> 2) << 7));
          acc0 = __builtin_amdgcn_mfma_f32_32x32x16_f16(af[0][kk], b, acc0, 0, 0, 0);
          acc1 = __builtin_amdgcn_mfma_f32_32x32x16_f16(af[1][kk], b, acc1, 0, 0, 0);
        }
        // positive scores -> raw bits unsigned-monotone;
        // pack (bits & ~1023)|(1023-code): umax == argmax, smaller-index ties
        const u32 invc = (u32)(code0 + col) ^ 1023u;
        #pragma unroll
        for (int i = 0; i < 16; ++i) {
          u32 p0 = (__float_as_uint(acc0[i]) & 0xFFFFFC00u) | invc;
          if (p0 > best[0][i]) best[0][i] = p0;
          u32 p1 = (__float_as_uint(acc1[i]) & 0xFFFFFC00u) | invc;
          if (p1 > best[1][i]) best[1][i] = p1;
        }
      }
    }

    // reduce best across the 32 code lanes (within each Lhi half)
    #pragma unroll
    for (int mt = 0; mt < 2; ++mt)
      #pragma unroll
      for (int i = 0; i < 16; ++i) {
        u32 b = best[mt][i];
        #pragma unroll
        for (int off = 1; off < 32; off <<= 1) {
          u32 o = __shfl_xor(b, off, 32);
          if (o > b) b = o;
        }
        best[mt][i] = b;
      }

    if (col == 0) {  // lanes 0 and 32: each half owns its token rows
      #pragma unroll
      for (int mt = 0; mt < 2; ++mt)
        #pragma unroll
        for (int i = 0; i < 16; ++i) {
          const u32 p = best[mt][i];
          const int code = (int)((p & 1023u) ^ 1023u);
          const int t = wave * 64 + mt * 32 + (i & 3) + 8 * (i >> 2) + 4 * Lhi;
          idx_hist[t][lvl] = code;
          const float sc = __uint_as_float(p & 0xFFFFFC00u) - 0.25f;  // r.e - e2/2
          commit_acc += r2_sh[t] - 2.0f * sc;  // dist = ||r||^2 - 2*sc
        }
    }
    __syncthreads();  // idx_hist visible; e2_lds free for next level

    if (lvl < LEVELS - 1) {  // fp16 residual update + next r2
      r2p[0] = 0.f; r2p[1] = 0.f;
      #pragma unroll
      for (int mt = 0; mt < 2; ++mt) {
        const int qidx = idx_hist[wave * 64 + mt * 32 + col][lvl];
        const _Float16* qr = cb16 + (((size_t)lvl << 10) + qidx) * DIM + Lhi * 8;
        #pragma unroll
        for (int kk = 0; kk < 16; ++kk) {
          h8 q = *(const h8*)(qr + kk * 16);
          h8 r = af[mt][kk] - q;
          af[mt][kk] = r;
          r2p[mt] = sq8(r, r2p[mt]);
        }
      }
    }
  }

  // ---- epilogue: y = sum_l q_l, fp32-exact, fully coalesced ----
  float* yblk = out + (size_t)blockIdx.x * (TOKB * DIM);
  #pragma unroll 4
  for (int it = 0; it < 64; ++it) {
    const int f = it * 512 + tid * 4;
    const int t = f >> 8;  // wave-uniform token
    const int d = f & 255;
    const int4 qi = *(const int4*)&idx_hist[t][0];
    f4 q0 = *(const f4*)(cb32 + (size_t)qi.x * DIM + d);
    f4 q1 = *(const f4*)(cb32 + (size_t)(1024 + qi.y) * DIM + d);
    f4 q2 = *(const f4*)(cb32 + (size_t)(2048 + qi.z) * DIM + d);
    f4 q3 = *(const f4*)(cb32 + (size_t)(3072 + qi.w) * DIM + d);
    f4 y = (q0 + q1) + (q2 + q3);
    *(f4*)(yblk + f) = y;
  }

  // ---- commit: butterfly + one atomic per block ----
  #pragma unroll
  for (int off = 1; off < 64; off <<= 1) commit_acc += __shfl_xor(commit_acc, off, 64);
  if (lane == 0) csum_sh[wave] = commit_acc;
  __syncthreads();
  if (tid == 0) {
    const float tot = csum_sh[0] + csum_sh[1];
    atomicAdd(out + NELEM, tot * (0.25f / 16777216.0f));  // BETA / (N*D)
  }
}

extern "C" void kernel_launch(void* const* d_in, const int* in_sizes, int n_in,
                              void* d_out, int out_size, void* d_ws, size_t ws_size,
                              hipStream_t stream) {
  const float* x = (const float*)d_in[0];
  const float* cb = (const float*)d_in[1];
  float* out = (float*)d_out;
  _Float16* cb16 = (_Float16*)d_ws;  // 2 MiB
  float* e2p = (float*)((char*)d_ws + (size_t)LEVELS * KCODES * DIM * sizeof(_Float16));

  rvq_prep<<<(LEVELS * KCODES) / 4, 256, 0, stream>>>(cb, cb16, e2p, out);
  rvq_main<<<NTOK / TOKB, 128, 0, stream>>>(x, cb, cb16, e2p, out);
}

// Round 5
// 270.430 us; speedup vs baseline: 1.1071x; 1.1071x over previous
//
#include <hip/hip_runtime.h>

#define DIM 256
#define KCODES 1024
#define LEVELS 4
#define CHUNK 64
#define NCHUNK 16
#define TOKB 128                 // 2 token-groups x 64 tokens; 4 waves
#define NTOK 65536
#define NELEM (NTOK * DIM)

typedef _Float16 h8 __attribute__((ext_vector_type(8)));
typedef _Float16 h4 __attribute__((ext_vector_type(4)));
typedef _Float16 h2 __attribute__((ext_vector_type(2)));
typedef float f4 __attribute__((ext_vector_type(4)));
typedef float f16v __attribute__((ext_vector_type(16)));
typedef unsigned int u32;

__device__ __forceinline__ void gload16(const void* g, void* l) {
  __builtin_amdgcn_global_load_lds(
      (const __attribute__((address_space(1))) void*)g,
      (__attribute__((address_space(3))) void*)l, 16, 0, 0);
}

__device__ __forceinline__ float sq8(h8 r, float acc) {
#if __has_builtin(__builtin_amdgcn_fdot2)
  #pragma unroll
  for (int j = 0; j < 4; ++j) {
    h2 p = {r[2 * j], r[2 * j + 1]};
    acc = __builtin_amdgcn_fdot2(p, p, acc, false);
  }
#else
  #pragma unroll
  for (int j = 0; j < 8; ++j) { float v = (float)r[j]; acc += v * v; }
#endif
  return acc;
}

// Phase 0: cb fp32 -> fp16; e2p = 0.25 - 0.5*||e||^2; zero commit accumulator.
__global__ __launch_bounds__(256) void rvq_prep(const float* __restrict__ cb,
                                                _Float16* __restrict__ cb16,
                                                float* __restrict__ e2p,
                                                float* __restrict__ out) {
  if (blockIdx.x == 0 && threadIdx.x == 0) out[NELEM] = 0.0f;
  const int row = blockIdx.x * 4 + (threadIdx.x >> 6);
  const int lane = threadIdx.x & 63;
  const float* src = cb + (size_t)row * DIM + lane * 4;
  f4 v = *(const f4*)src;
  h4 hv;
  hv[0] = (_Float16)v[0]; hv[1] = (_Float16)v[1];
  hv[2] = (_Float16)v[2]; hv[3] = (_Float16)v[3];
  *(h4*)(cb16 + (size_t)row * DIM + lane * 4) = hv;
  float s = v[0]*v[0] + v[1]*v[1] + v[2]*v[2] + v[3]*v[3];
  #pragma unroll
  for (int off = 32; off; off >>= 1) s += __shfl_xor(s, off, 64);
  if (lane == 0) e2p[row] = 0.25f - 0.5f * s;
}

// Main fused RVQ. 4 waves = 2 token-groups (64 tokens) x 2 code-half waves.
// Each wave scans HALF of each chunk's codes for its group's 64 tokens:
// LDS B-traffic per (token,code) pair is r4's halved rate, but wave count is
// 2048 -> 2 waves/SIMD (the r4 regression was 1 wave/SIMD latency exposure).
// Cross-wave argmax combine per level through a small LDS table.
__global__ __launch_bounds__(256, 2) void rvq_main(
    const float* __restrict__ x, const float* __restrict__ cb32,
    const _Float16* __restrict__ cb16, const float* __restrict__ e2p,
    float* __restrict__ out) {
  __shared__ __attribute__((aligned(16))) _Float16 clds[2][CHUNK * DIM];  // 64 KB
  __shared__ float e2_lds[KCODES];                                        // 4 KB
  __shared__ __attribute__((aligned(16))) int idx_hist[TOKB][4];          // 2 KB
  __shared__ float r2_sh[TOKB];                                           // 512 B
  __shared__ u32 bestsh[4][64];                                           // 1 KB [grp*2+half][e]
  __shared__ float csum_sh[4];

  const int tid = threadIdx.x;
  const int wave = tid >> 6, lane = tid & 63;
  const int col = lane & 31, Lhi = lane >> 5;
  const int group = wave >> 1, half = wave & 1;

  // staging: call i covers rows (wave*16 + 2i + Lhi); lane fills row position
  // p = col with global granule g = p ^ (row&7) (XOR swizzle, self-inverse).
  int soff[8];
  #pragma unroll
  for (int i = 0; i < 8; ++i) {
    const int rl = wave * 16 + 2 * i + Lhi;
    soff[i] = rl * 512 + ((col ^ (rl & 7)) << 4);
  }
  // read swizzle: granule g = 2kk+Lhi of row (half*32+col); row&7 == col&7
  int swz4[4];
  #pragma unroll
  for (int m = 0; m < 4; ++m)
    swz4[m] = (((((m << 1) | Lhi) ^ col) & 7) << 4);

  const char* cb16b = (const char*)cb16;
  // issue chunk 0 staging immediately; flies during x-init
  {
    char* ldst = (char*)&clds[0][0] + wave * 8192;
    #pragma unroll
    for (int i = 0; i < 8; ++i) gload16(cb16b + soff[i], ldst + i * 1024);
  }

  // ---- init: x -> fp16 A-frags + r2 partials (both halves load same rows;
  // second read is L2-hot) ----
  h8 af[2][16];
  float r2p[2] = {0.f, 0.f};
  const size_t tok0 = (size_t)blockIdx.x * TOKB + group * 64;
  #pragma unroll
  for (int mt = 0; mt < 2; ++mt) {
    const float* xr = x + (tok0 + mt * 32 + col) * DIM + Lhi * 8;
    #pragma unroll
    for (int kk = 0; kk < 16; ++kk) {
      f4 a = *(const f4*)(xr + kk * 16);
      f4 b = *(const f4*)(xr + kk * 16 + 4);
      h8 h;
      #pragma unroll
      for (int j = 0; j < 4; ++j) { h[j] = (_Float16)a[j]; h[4 + j] = (_Float16)b[j]; }
      af[mt][kk] = h;
      r2p[mt] = sq8(h, r2p[mt]);
    }
  }

  float commit_acc = 0.f;

  for (int lvl = 0; lvl < LEVELS; ++lvl) {
    // residual norms -> LDS (half-0 wave writes; both halves have same values)
    #pragma unroll
    for (int mt = 0; mt < 2; ++mt) {
      float s = r2p[mt] + __shfl_xor(r2p[mt], 32, 64);
      if (half == 0 && Lhi == 0) r2_sh[group * 64 + mt * 32 + col] = s;
    }
    // this level's shifted-e2 table
    *(f4*)&e2_lds[tid * 4] = *(const f4*)(e2p + (lvl << 10) + tid * 4);

    u32 best[2][16];
    #pragma unroll
    for (int mt = 0; mt < 2; ++mt)
      #pragma unroll
      for (int i = 0; i < 16; ++i) best[mt][i] = 0u;

    for (int c = 0; c < NCHUNK; ++c) {
      __syncthreads();  // staging of chunk c (issued a full phase ago) visible
      {
        const int gn = lvl * NCHUNK + c + 1;  // contiguous across levels
        const char* gsrc = cb16b + ((size_t)(gn < 64 ? gn : 63) << 15);
        char* ldst = (char*)&clds[(c + 1) & 1][0] + wave * 8192;
        #pragma unroll
        for (int i = 0; i < 8; ++i) gload16(gsrc + soff[i], ldst + i * 1024);
      }

      // this wave scans its half's 32 codes: rows half*32 + col
      const int code0 = c * 64 + half * 32;
      const char* bptr = (const char*)&clds[c & 1][0] + (half * 32 + col) * 512;
      const float e2v = e2_lds[code0 + col];  // 0.25 - ||e||^2/2
      f16v acc0, acc1;
      #pragma unroll
      for (int i = 0; i < 16; ++i) { acc0[i] = e2v; acc1[i] = e2v; }
      #pragma unroll
      for (int kk = 0; kk < 16; ++kk) {
        h8 b = *(const h8*)(bptr + swz4[kk & 3] + ((kk >> 2) << 7));
        acc0 = __builtin_amdgcn_mfma_f32_32x32x16_f16(af[0][kk], b, acc0, 0, 0, 0);
        acc1 = __builtin_amdgcn_mfma_f32_32x32x16_f16(af[1][kk], b, acc1, 0, 0, 0);
      }
      // positive scores -> raw bits unsigned-monotone;
      // pack (bits & ~1023)|(1023-code): umax == argmax, smaller-index ties
      const u32 invc = (u32)(code0 + col) ^ 1023u;
      #pragma unroll
      for (int i = 0; i < 16; ++i) {
        u32 p0 = (__float_as_uint(acc0[i]) & 0xFFFFFC00u) | invc;
        if (p0 > best[0][i]) best[0][i] = p0;
        u32 p1 = (__float_as_uint(acc1[i]) & 0xFFFFFC00u) | invc;
        if (p1 > best[1][i]) best[1][i] = p1;
      }
    }

    // reduce across the 32 code lanes (within each Lhi half; butterfly ->
    // every lane of the half holds the max for its token rows)
    #pragma unroll
    for (int mt = 0; mt < 2; ++mt)
      #pragma unroll
      for (int i = 0; i < 16; ++i) {
        u32 b = best[mt][i];
        #pragma unroll
        for (int off = 1; off < 32; off <<= 1) {
          u32 o = __shfl_xor(b, off, 32);
          if (o > b) b = o;
        }
        best[mt][i] = b;
      }

    // publish this wave's half-codebook result (lanes 0 and 32)
    if (col == 0) {
      #pragma unroll
      for (int mt = 0; mt < 2; ++mt)
        #pragma unroll
        for (int i = 0; i < 16; ++i)
          bestsh[wave][mt * 32 + i * 2 + Lhi] = best[mt][i];
    }
    __syncthreads();

    // combine halves: half-0 wave, one entry per lane (64 entries/group)
    if (half == 0) {
      const int e = lane;                 // e = mt*32 + i*2 + Lhi_t
      const int mt = e >> 5, i = (e >> 1) & 15, lh = e & 1;
      u32 p0 = bestsh[group * 2 + 0][e];
      u32 p1 = bestsh[group * 2 + 1][e];
      const u32 p = p0 > p1 ? p0 : p1;
      const int code = (int)((p & 1023u) ^ 1023u);
      const int t = group * 64 + mt * 32 + (i & 3) + 8 * (i >> 2) + 4 * lh;
      idx_hist[t][lvl] = code;
      const float sc = __uint_as_float(p & 0xFFFFFC00u) - 0.25f;  // r.e - e2/2
      commit_acc += r2_sh[t] - 2.0f * sc;   // dist = ||r||^2 - 2*sc
    }
    __syncthreads();  // idx_hist visible to both halves

    if (lvl < LEVELS - 1) {  // fp16 residual update + next r2 (both halves)
      r2p[0] = 0.f; r2p[1] = 0.f;
      #pragma unroll
      for (int mt = 0; mt < 2; ++mt) {
        const int qidx = idx_hist[group * 64 + mt * 32 + col][lvl];
        const _Float16* qr = cb16 + (((size_t)lvl << 10) + qidx) * DIM + Lhi * 8;
        #pragma unroll
        for (int kk = 0; kk < 16; ++kk) {
          h8 q = *(const h8*)(qr + kk * 16);
          h8 r = af[mt][kk] - q;
          af[mt][kk] = r;
          r2p[mt] = sq8(r, r2p[mt]);
        }
      }
    }
  }

  // ---- epilogue: y = sum_l q_l, fp32-exact, fully coalesced ----
  float* yblk = out + (size_t)blockIdx.x * (TOKB * DIM);
  #pragma unroll 4
  for (int it = 0; it < 32; ++it) {
    const int f = it * 1024 + tid * 4;
    const int t = f >> 8;  // wave-uniform token
    const int d = f & 255;
    const int4 qi = *(const int4*)&idx_hist[t][0];
    f4 q0 = *(const f4*)(cb32 + (size_t)qi.x * DIM + d);
    f4 q1 = *(const f4*)(cb32 + (size_t)(1024 + qi.y) * DIM + d);
    f4 q2 = *(const f4*)(cb32 + (size_t)(2048 + qi.z) * DIM + d);
    f4 q3 = *(const f4*)(cb32 + (size_t)(3072 + qi.w) * DIM + d);
    f4 y = (q0 + q1) + (q2 + q3);
    *(f4*)(yblk + f) = y;
  }

  // ---- commit: butterfly + one atomic per block (waves 1,3 contribute 0) ----
  #pragma unroll
  for (int off = 1; off < 64; off <<= 1) commit_acc += __shfl_xor(commit_acc, off, 64);
  if (lane == 0) csum_sh[wave] = commit_acc;
  __syncthreads();
  if (tid == 0) {
    const float tot = csum_sh[0] + csum_sh[1] + csum_sh[2] + csum_sh[3];
    atomicAdd(out + NELEM, tot * (0.25f / 16777216.0f));  // BETA / (N*D)
  }
}

extern "C" void kernel_launch(void* const* d_in, const int* in_sizes, int n_in,
                              void* d_out, int out_size, void* d_ws, size_t ws_size,
                              hipStream_t stream) {
  const float* x = (const float*)d_in[0];
  const float* cb = (const float*)d_in[1];
  float* out = (float*)d_out;
  _Float16* cb16 = (_Float16*)d_ws;  // 2 MiB
  float* e2p = (float*)((char*)d_ws + (size_t)LEVELS * KCODES * DIM * sizeof(_Float16));

  rvq_prep<<<(LEVELS * KCODES) / 4, 256, 0, stream>>>(cb, cb16, e2p, out);
  rvq_main<<<NTOK / TOKB, 256, 0, stream>>>(x, cb, cb16, e2p, out);
}